// Round 12
// baseline (2761.892 us; speedup 1.0000x reference)
//
#include <hip/hip_runtime.h>

#define DEV __device__ __forceinline__
typedef __attribute__((ext_vector_type(8))) short s16x8;
typedef __attribute__((ext_vector_type(4))) float f32x4;
typedef __attribute__((ext_vector_type(4))) int i32x4;
typedef unsigned short u16;

// ---------- constants ----------
#define NB 16      // B
#define TPN 2
#define NODES 8192
#define D 128
#define P 256
#define NPS 32
#define OUT_LEN 12

DEV f32x4 mfma16(s16x8 a, s16x8 b, f32x4 c) {
  return __builtin_amdgcn_mfma_f32_16x16x32_bf16(a, b, c, 0, 0, 0);
}

DEV short f2bf(float f) {
  union { float f; unsigned u; } v; v.f = f;
  unsigned r = v.u + 0x7fffu + ((v.u >> 16) & 1u);
  return (short)(r >> 16);
}

// swizzled LDS addressing: 256B-row and 512B-row buffers, XOR bits 4-6 by row&7
DEV int swz256(int row, int b) { return (row << 8) + (b ^ ((row & 7) << 4)); }
DEV int swz512(int row, int b) { return (row << 9) + (b ^ ((row & 7) << 4)); }

// A-fragment load: lane l -> row = mbase+(l&15), k = kbase+(l>>4)*8 .. +8
DEV s16x8 ldsA(const char* base, int mbase, int kbase, int lane) {
  int row = mbase + (lane & 15);
  int b = (kbase + ((lane >> 4) << 3)) << 1;
  return *(const s16x8*)(base + swz256(row, b));
}

// butterfly reduce across lane bits 0..3 (16-lane row groups)
DEV float rowred(float v) {
  v += __shfl_xor(v, 1);
  v += __shfl_xor(v, 2);
  v += __shfl_xor(v, 4);
  v += __shfl_xor(v, 8);
  return v;
}
// reduce across g-groups (lane bits 4,5): full 128-col row sum for A-layout
DEV float gred(float v) {
  v += __shfl_xor(v, 16);
  v += __shfl_xor(v, 32);
  return v;
}

// stage one 64-col x 128-k bf16 weight tile (16KB) into LDS, swz256 layout (1024 threads).
DEV void stageW(char* buf, const u16* __restrict__ w, int tid) {
  int col = tid >> 4, kc = tid & 15;
  s16x8 v = *(const s16x8*)(w + col * 128 + kc * 8);
  *(s16x8*)(buf + swz256(col, kc * 16)) = v;
}

// ---------------- weight prep: f32 [3][K][N] -> bf16 [3][N][K] ----------------
__global__ void k_prep(const float* __restrict__ src, u16* __restrict__ dst, int K, int N) {
  int idx = blockIdx.x * 256 + threadIdx.x;
  int total = 3 * K * N;
  if (idx >= total) return;
  int l = idx / (K * N);
  int r = idx - l * K * N;
  int n = r / K;
  int k = r - n * K;
  dst[idx] = (u16)f2bf(src[l * K * N + k * N + n]);
}

// ---------------- embedding (scatter form) ----------------
__global__ __launch_bounds__(256) void k_embed(
    const float* __restrict__ x, const int* __restrict__ te, const int* __restrict__ reo_parts,
    const float* __restrict__ w_st, const float* __restrict__ b_st,
    const float* __restrict__ node_emb, const float* __restrict__ tod_emb,
    const float* __restrict__ dow_emb, float* __restrict__ rex) {
  __shared__ float sx[12][16], s0[12][16], s1[12][16];
  __shared__ int sed[2][16];
  __shared__ int sj[16];
  __shared__ float hb[16][132];
  int gid = blockIdx.x;
  int chunk = gid & 511, bt = gid >> 9;
  int b = bt >> 1, tt = bt & 1;
  int tid = threadIdx.x;
  int nl = tid & 15, c = tid >> 4;
  int n = chunk * 16 + nl;
  if (c < 12) {
    size_t off = ((size_t)(b * 24 + tt * 12 + c)) * NODES + n;
    sx[c][nl] = x[off];
    int2 t2 = *(const int2*)(te + 2 * off);
    s0[c][nl] = (float)t2.x * (1.0f / 288.0f);
    s1[c][nl] = (float)t2.y * (1.0f / 7.0f);
  } else if (c == 12) {
    size_t off = ((size_t)(b * 24 + 22 + tt)) * NODES + n;
    int2 t2 = *(const int2*)(te + 2 * off);
    sed[0][nl] = t2.x;
    sed[1][nl] = t2.y;
  } else if (c == 13) {
    sj[nl] = reo_parts[n];
  }
  __syncthreads();
  int db = c * 8;
  float o[8];
#pragma unroll
  for (int dd = 0; dd < 8; ++dd) {
    int d = db + dd;
    float v;
    if (d < 64) {
      float acc = b_st[d];
      const float* wd = w_st + d * 36;
#pragma unroll
      for (int p = 0; p < 12; ++p)
        acc += sx[p][nl] * wd[p] + s0[p][nl] * wd[12 + p] + s1[p][nl] * wd[24 + p];
      v = acc;
    } else if (d < 80) {
      v = tod_emb[sed[0][nl] * 16 + (d - 64)];
    } else if (d < 96) {
      v = dow_emb[sed[1][nl] * 16 + (d - 80)];
    } else {
      v = node_emb[n * 32 + (d - 96)];
    }
    o[dd] = v;
  }
  *(float4*)&hb[nl][db] = make_float4(o[0], o[1], o[2], o[3]);
  *(float4*)&hb[nl][db + 4] = make_float4(o[4], o[5], o[6], o[7]);
  __syncthreads();
  int row = tid >> 4, cw = tid & 15;
  float4 v0 = *(float4*)&hb[row][cw * 8];
  float4 v1 = *(float4*)&hb[row][cw * 8 + 4];
  float* dst = rex + ((size_t)bt * NODES + sj[row]) * D + cw * 8;
  *(float4*)dst = v0;
  *(float4*)(dst + 4) = v1;
}

// ---------------- fused transformer sublayer pair: 16 waves x 16 tokens, staged weights ----
// 1024 threads = 16 waves = 4 waves/SIMD. Unified-file split gives ~64 arch regs/wave, so
// EVERY phase keeps its scalar live set < 64: the f32 residual is never held across a GEMM
// phase. After proj, X' = X + delta is written back to rex (plain/cached stores) and
// reloaded (same lane, same bytes; L2-resident) at fc2. Barriers between drain vmcnt.
// CROSS=true : token stride 4096, full-256 attention; CROSS=false: stride 128, per-patch.
// LDS map: Kb[0,64K) | VT[64K,128K) | WS[128K,160K). Aliases: scrQ=VT (pre-V, 4KB/wave),
// scrO=Kb (post-attn, 4KB/wave), Pscr in WS (attention phase). X staged coop in sm[0,128K).
template <bool CROSS>
__global__ __launch_bounds__(1024, 4) void k_fused(
    float* __restrict__ rex,
    const u16* __restrict__ wqkv, const float* __restrict__ bqkv,
    const u16* __restrict__ wprj, const float* __restrict__ bprj,
    const u16* __restrict__ w1t, const float* __restrict__ b1,
    const u16* __restrict__ w2t, const float* __restrict__ b2) {
  __shared__ __align__(16) char sm[163840];
  char* Kb = sm;
  char* VT = sm + 65536;
  char* WSa = sm + 131072;
  char* WSb = sm + 147456;
  int tid = threadIdx.x;
  int w = tid >> 6, lane = tid & 63;
  int r = lane & 15, g = lane >> 4;
  char* scrQ = sm + 65536 + w * 4096;   // pre-V wave scratch (VT alias)
  char* scrO = sm + w * 4096;           // post-attn wave scratch (Kb alias)
  char* Pscr = sm + 131072 + w * 1280;  // P tiles (WS alias, attention phase only)

  int sq = blockIdx.x;
  const int TS = CROSS ? (NPS * D) : D;  // token stride in floats
  const size_t TSB = (size_t)TS * 4;
  float* Xblk;
  if (CROSS) {
    int bt = sq >> 5, i = sq & 31;
    Xblk = rex + (size_t)bt * (NODES * D) + i * D;
  } else {
    Xblk = rex + (size_t)sq * (256 * D);
  }

  // ---- cooperative X load: 256 rows x 512B contiguous (cached: L3 reuse across layers)
#pragma unroll
  for (int it = 0; it < 8; ++it) {
    int unit = it * 1024 + tid;
    int row = unit >> 5, col = unit & 31;
    i32x4 v = *(const i32x4*)((const char*)Xblk + (size_t)row * TSB + col * 16);
    *(i32x4*)(sm + (row << 9) + ((col * 16) ^ ((row & 7) << 4))) = v;
  }
  stageW(WSa, wqkv, tid);
  __syncthreads();

  // ---- LN1: transient row regs -> ax fragments only (residual NOT kept live)
  int myrow = w * 16 + r;
  s16x8 ax[4];
  {
    float xt[4][8];
#pragma unroll
    for (int kt = 0; kt < 4; ++kt) {
      f32x4 u0 = *(const f32x4*)(sm + (myrow << 9) + ((kt * 128 + g * 32) ^ ((myrow & 7) << 4)));
      f32x4 u1 = *(const f32x4*)(sm + (myrow << 9) + ((kt * 128 + g * 32 + 16) ^ ((myrow & 7) << 4)));
      xt[kt][0] = u0[0]; xt[kt][1] = u0[1]; xt[kt][2] = u0[2]; xt[kt][3] = u0[3];
      xt[kt][4] = u1[0]; xt[kt][5] = u1[1]; xt[kt][6] = u1[2]; xt[kt][7] = u1[3];
    }
    float s = 0.f, s2 = 0.f;
#pragma unroll
    for (int kt = 0; kt < 4; ++kt)
#pragma unroll
      for (int j = 0; j < 8; ++j) { float v = xt[kt][j]; s += v; s2 += v * v; }
    s = gred(s); s2 = gred(s2);
    float m = s * 0.0078125f;
    float rsd = rsqrtf(s2 * 0.0078125f - m * m + 1e-6f);
#pragma unroll
    for (int kt = 0; kt < 4; ++kt) {
      s16x8 o;
#pragma unroll
      for (int j = 0; j < 8; ++j) o[j] = f2bf((xt[kt][j] - m) * rsd);
      ax[kt] = o;
    }
  }
  __syncthreads();  // X staging consumed; Kb/VT writable

  // ---- QKV: 6 staged 64-col tiles (Q:0-1 -> scrQ, K:2-3 -> Kb, V:4-5 -> VT)
  s16x8 aq[4];
  for (int t = 0; t < 6; ++t) {
    const char* cur = (t & 1) ? WSb : WSa;
    if (t < 5) stageW((t & 1) ? WSa : WSb, wqkv + (size_t)(t + 1) * 8192, tid);
#pragma unroll
    for (int sub = 0; sub < 4; ++sub) {
      int colg = t * 64 + sub * 16 + r;
      f32x4 acc = {0.f, 0.f, 0.f, 0.f};
#pragma unroll
      for (int kt = 0; kt < 4; ++kt)
        acc = mfma16(ax[kt], ldsA(cur, sub * 16, kt * 32, lane), acc);
      float bias = bqkv[colg];
#pragma unroll
      for (int e = 0; e < 4; ++e) {
        float v = acc[e] + bias;
        int tok = w * 16 + g * 4 + e;
        if (t < 2) {
          *(u16*)(scrQ + swz256(g * 4 + e, colg * 2)) = (u16)f2bf(v);
        } else if (t < 4) {
          *(u16*)(Kb + swz256(tok, (colg - 128) * 2)) = (u16)f2bf(v);
        } else {
          *(u16*)(VT + swz512(colg - 256, tok * 2)) = (u16)f2bf(v);
        }
      }
    }
    if (t == 1) {
#pragma unroll
      for (int kt = 0; kt < 4; ++kt) aq[kt] = ldsA(scrQ, 0, kt * 32, lane);
    }
    __syncthreads();
  }

  const float scale = 0.08838834764831845f;
  float sum[4] = {0.f, 0.f, 0.f, 0.f};
  f32x4 av[8];
#pragma unroll
  for (int nt = 0; nt < 8; ++nt) av[nt] = (f32x4){0.f, 0.f, 0.f, 0.f};

  if (CROSS) {
    // ---- scores vs all 256 keys; exp w/o max-pass; per-32k chunk P staging + AV
    for (int cc = 0; cc < 8; ++cc) {
#pragma unroll
      for (int sub = 0; sub < 2; ++sub) {
        int kt2 = cc * 2 + sub;
        f32x4 acc = {0.f, 0.f, 0.f, 0.f};
#pragma unroll
        for (int kt = 0; kt < 4; ++kt) {
          s16x8 b = ldsA(Kb, kt2 * 16, kt * 32, lane);
          acc = mfma16(aq[kt], b, acc);
        }
#pragma unroll
        for (int e = 0; e < 4; ++e) {
          float p = __expf(acc[e] * scale);
          sum[e] += p;
          *(u16*)(Pscr + (g * 4 + e) * 80 + (sub * 16 + r) * 2) = (u16)f2bf(p);
        }
      }
      s16x8 ap = *(const s16x8*)(Pscr + r * 80 + g * 16);
#pragma unroll
      for (int nt = 0; nt < 8; ++nt) {
        s16x8 bv = *(const s16x8*)(VT + swz512(nt * 16 + r, (cc * 32 + g * 8) * 2));
        av[nt] = mfma16(ap, bv, av[nt]);
      }
    }
  } else {
    // ---- per-patch attention: patch pw = w>>1 owns tokens pw*32..pw*32+31
    int pw = w >> 1;
#pragma unroll
    for (int sub = 0; sub < 2; ++sub) {
      f32x4 acc = {0.f, 0.f, 0.f, 0.f};
#pragma unroll
      for (int kt = 0; kt < 4; ++kt) {
        s16x8 b = ldsA(Kb, pw * 32 + sub * 16, kt * 32, lane);
        acc = mfma16(aq[kt], b, acc);
      }
#pragma unroll
      for (int e = 0; e < 4; ++e) {
        float p = __expf(acc[e] * scale);
        sum[e] += p;
        *(u16*)(Pscr + (g * 4 + e) * 80 + (sub * 16 + r) * 2) = (u16)f2bf(p);
      }
    }
    s16x8 ap = *(const s16x8*)(Pscr + r * 80 + g * 16);
#pragma unroll
    for (int nt = 0; nt < 8; ++nt) {
      s16x8 bv = *(const s16x8*)(VT + swz512(nt * 16 + r, (pw * 32 + g * 8) * 2));
      f32x4 z = {0.f, 0.f, 0.f, 0.f};
      av[nt] = mfma16(ap, bv, z);
    }
  }
#pragma unroll
  for (int e = 0; e < 4; ++e) sum[e] = rowred(sum[e]);
  __syncthreads();  // Kb/VT reads done -> scrO & WS reusable

  // ---- normalize AV -> scrO (bf16) -> aav
  s16x8 aav[4];
  {
    float rinv[4];
#pragma unroll
    for (int e = 0; e < 4; ++e) rinv[e] = 1.0f / sum[e];
#pragma unroll
    for (int nt = 0; nt < 8; ++nt)
#pragma unroll
      for (int e = 0; e < 4; ++e)
        *(u16*)(scrO + swz256(g * 4 + e, (nt * 16 + r) * 2)) = (u16)f2bf(av[nt][e] * rinv[e]);
#pragma unroll
    for (int kt = 0; kt < 4; ++kt) aav[kt] = ldsA(scrO, 0, kt * 32, lane);
  }

  // ---- read X row from global (L3-resident) for the attention residual
  float xr[4][8];
  {
    const float* Xrow = (const float*)((const char*)Xblk + (size_t)myrow * TSB);
#pragma unroll
    for (int kt = 0; kt < 4; ++kt) {
      float4 a = *(const float4*)(Xrow + kt * 32 + g * 8);
      float4 b = *(const float4*)(Xrow + kt * 32 + g * 8 + 4);
      xr[kt][0] = a.x; xr[kt][1] = a.y; xr[kt][2] = a.z; xr[kt][3] = a.w;
      xr[kt][4] = b.x; xr[kt][5] = b.y; xr[kt][6] = b.z; xr[kt][7] = b.w;
    }
  }

  // ---- proj: 2 staged tiles, C-out -> f32 bounce -> xr (A-layout)
  stageW(WSa, wprj, tid);
  __syncthreads();
#pragma unroll
  for (int t = 0; t < 2; ++t) {
    const char* cur = t ? WSb : WSa;
    if (t == 0) stageW(WSb, wprj + 8192, tid);
#pragma unroll
    for (int sub = 0; sub < 4; ++sub) {
      int colg = t * 64 + sub * 16 + r;
      f32x4 acc = {0.f, 0.f, 0.f, 0.f};
#pragma unroll
      for (int kt = 0; kt < 4; ++kt)
        acc = mfma16(aav[kt], ldsA(cur, sub * 16, kt * 32, lane), acc);
      float bias = bprj[colg];
#pragma unroll
      for (int e = 0; e < 4; ++e) {
        int row = g * 4 + e;
        *(float*)(scrO + row * 256 + (((sub * 16 + r) * 4) ^ ((row & 7) << 4))) = acc[e] + bias;
      }
    }
#pragma unroll
    for (int kk = 0; kk < 2; ++kk) {
      int base = kk * 128 + g * 32;
      f32x4 u0 = *(const f32x4*)(scrO + r * 256 + (base ^ ((r & 7) << 4)));
      f32x4 u1 = *(const f32x4*)(scrO + r * 256 + ((base + 16) ^ ((r & 7) << 4)));
      int kt = t * 2 + kk;
      xr[kt][0] += u0[0]; xr[kt][1] += u0[1]; xr[kt][2] += u0[2]; xr[kt][3] += u0[3];
      xr[kt][4] += u1[0]; xr[kt][5] += u1[1]; xr[kt][6] += u1[2]; xr[kt][7] += u1[3];
    }
    __syncthreads();
  }

  // ---- LN2 from X'; write X' back to rex (manual residual "spill"); xr dies here
  s16x8 ah[4];
  {
    float s = 0.f, s2 = 0.f;
#pragma unroll
    for (int kt = 0; kt < 4; ++kt)
#pragma unroll
      for (int j = 0; j < 8; ++j) { float v = xr[kt][j]; s += v; s2 += v * v; }
    s = gred(s); s2 = gred(s2);
    float m = s * 0.0078125f;
    float rsd = rsqrtf(s2 * 0.0078125f - m * m + 1e-6f);
#pragma unroll
    for (int kt = 0; kt < 4; ++kt) {
      s16x8 o;
#pragma unroll
      for (int j = 0; j < 8; ++j) o[j] = f2bf((xr[kt][j] - m) * rsd);
      ah[kt] = o;
    }
    float* Xrow = (float*)((char*)Xblk + (size_t)myrow * TSB);
#pragma unroll
    for (int kt = 0; kt < 4; ++kt) {
      *(float4*)(Xrow + kt * 32 + g * 8) =
          make_float4(xr[kt][0], xr[kt][1], xr[kt][2], xr[kt][3]);
      *(float4*)(Xrow + kt * 32 + g * 8 + 4) =
          make_float4(xr[kt][4], xr[kt][5], xr[kt][6], xr[kt][7]);
    }
  }

  // ---- fc1 + gelu -> scrO bf16 (only ah live across this phase)
  stageW(WSa, w1t, tid);
  __syncthreads();
  s16x8 ah2[4];
#pragma unroll
  for (int t = 0; t < 2; ++t) {
    const char* cur = t ? WSb : WSa;
    if (t == 0) stageW(WSb, w1t + 8192, tid);
#pragma unroll
    for (int sub = 0; sub < 4; ++sub) {
      int colg = t * 64 + sub * 16 + r;
      f32x4 acc = {0.f, 0.f, 0.f, 0.f};
#pragma unroll
      for (int kt = 0; kt < 4; ++kt)
        acc = mfma16(ah[kt], ldsA(cur, sub * 16, kt * 32, lane), acc);
      float bias = b1[colg];
#pragma unroll
      for (int e = 0; e < 4; ++e) {
        float v0 = acc[e] + bias;
        v0 = 0.5f * v0 * (1.0f + erff(v0 * 0.70710678118654752f));
        *(u16*)(scrO + swz256(g * 4 + e, colg * 2)) = (u16)f2bf(v0);
      }
    }
    if (t == 1) {
#pragma unroll
      for (int kt = 0; kt < 4; ++kt) ah2[kt] = ldsA(scrO, 0, kt * 32, lane);
    }
    __syncthreads();
  }

  // ---- reload X' (same lane, same bytes; L2-resident) for the MLP residual
  {
    const float* Xrow = (const float*)((const char*)Xblk + (size_t)myrow * TSB);
#pragma unroll
    for (int kt = 0; kt < 4; ++kt) {
      float4 a = *(const float4*)(Xrow + kt * 32 + g * 8);
      float4 b = *(const float4*)(Xrow + kt * 32 + g * 8 + 4);
      xr[kt][0] = a.x; xr[kt][1] = a.y; xr[kt][2] = a.z; xr[kt][3] = a.w;
      xr[kt][4] = b.x; xr[kt][5] = b.y; xr[kt][6] = b.z; xr[kt][7] = b.w;
    }
  }

  // ---- fc2: 2 staged tiles, C-out -> f32 bounce -> xr
  stageW(WSa, w2t, tid);
  __syncthreads();
#pragma unroll
  for (int t = 0; t < 2; ++t) {
    const char* cur = t ? WSb : WSa;
    if (t == 0) stageW(WSb, w2t + 8192, tid);
#pragma unroll
    for (int sub = 0; sub < 4; ++sub) {
      int colg = t * 64 + sub * 16 + r;
      f32x4 acc = {0.f, 0.f, 0.f, 0.f};
#pragma unroll
      for (int kt = 0; kt < 4; ++kt)
        acc = mfma16(ah2[kt], ldsA(cur, sub * 16, kt * 32, lane), acc);
      float bias = b2[colg];
#pragma unroll
      for (int e = 0; e < 4; ++e) {
        int row = g * 4 + e;
        *(float*)(scrO + row * 256 + (((sub * 16 + r) * 4) ^ ((row & 7) << 4))) = acc[e] + bias;
      }
    }
#pragma unroll
    for (int kk = 0; kk < 2; ++kk) {
      int base = kk * 128 + g * 32;
      f32x4 u0 = *(const f32x4*)(scrO + r * 256 + (base ^ ((r & 7) << 4)));
      f32x4 u1 = *(const f32x4*)(scrO + r * 256 + ((base + 16) ^ ((r & 7) << 4)));
      int kt = t * 2 + kk;
      xr[kt][0] += u0[0]; xr[kt][1] += u0[1]; xr[kt][2] += u0[2]; xr[kt][3] += u0[3];
      xr[kt][4] += u1[0]; xr[kt][5] += u1[1]; xr[kt][6] += u1[2]; xr[kt][7] += u1[3];
    }
    if (t == 0) __syncthreads();
  }

  // ---- cooperative X store: rows to LDS, then contiguous write-out (cached: L3 reuse)
  __syncthreads();  // all waves done with scrO region
#pragma unroll
  for (int kt = 0; kt < 4; ++kt) {
    *(f32x4*)(sm + (myrow << 9) + ((kt * 128 + g * 32) ^ ((myrow & 7) << 4))) =
        (f32x4){xr[kt][0], xr[kt][1], xr[kt][2], xr[kt][3]};
    *(f32x4*)(sm + (myrow << 9) + ((kt * 128 + g * 32 + 16) ^ ((myrow & 7) << 4))) =
        (f32x4){xr[kt][4], xr[kt][5], xr[kt][6], xr[kt][7]};
  }
  __syncthreads();
#pragma unroll
  for (int it = 0; it < 8; ++it) {
    int unit = it * 1024 + tid;
    int row = unit >> 5, col = unit & 31;
    i32x4 v = *(const i32x4*)(sm + (row << 9) + ((col * 16) ^ ((row & 7) << 4)));
    *(i32x4*)((char*)Xblk + (size_t)row * TSB + col * 16) = v;
  }
}

// ---------------- readout ----------------
__global__ __launch_bounds__(256) void k_readout(
    const float* __restrict__ rex, const int* __restrict__ ori_idx,
    const int* __restrict__ reo_idx, const float* __restrict__ w_reg,
    const float* __restrict__ b_reg, float* __restrict__ out) {
  __shared__ float wl[3072];
  for (int i2 = threadIdx.x; i2 < 3072; i2 += 256) wl[i2] = w_reg[i2];
  __syncthreads();
  int b = blockIdx.x >> 7;
  int chunk = blockIdx.x & 127;
  int m = chunk * 64 + (threadIdx.x >> 2);
  int q = threadIdx.x & 3;
  int nOut = ori_idx[m];
  int j = reo_idx[m];
  int t = q >> 1;
  const float* src = rex + ((size_t)(b * 2 + t) * NODES + j) * D + (q & 1) * 64;
  float acc[12] = {0.f, 0.f, 0.f, 0.f, 0.f, 0.f, 0.f, 0.f, 0.f, 0.f, 0.f, 0.f};
#pragma unroll
  for (int k = 0; k < 64; k += 4) {
    float4 v = *(const float4*)(src + k);
#pragma unroll
    for (int o = 0; o < 12; ++o) {
      float4 wv = *(const float4*)(&wl[o * 256 + q * 64 + k]);
      acc[o] += v.x * wv.x + v.y * wv.y + v.z * wv.z + v.w * wv.w;
    }
  }
#pragma unroll
  for (int o = 0; o < 12; ++o) {
    acc[o] += __shfl_xor(acc[o], 1);
    acc[o] += __shfl_xor(acc[o], 2);
  }
  if (q == 0) {
#pragma unroll
    for (int o = 0; o < 12; ++o)
      out[((size_t)b * 12 + o) * NODES + nOut] = acc[o] + b_reg[o];
  }
}

// ---------------- host ----------------
extern "C" void kernel_launch(void* const* d_in, const int* in_sizes, int n_in,
                              void* d_out, int out_size, void* d_ws, size_t ws_size,
                              hipStream_t stream) {
  (void)in_sizes; (void)n_in; (void)out_size;
  const float* x = (const float*)d_in[0];
  const int* te = (const int*)d_in[1];
  const int* reo_all = (const int*)d_in[2];
  const int* ori_parts = (const int*)d_in[3];
  const int* reo_parts = (const int*)d_in[4];
  const float* w_st = (const float*)d_in[5];
  const float* b_st = (const float*)d_in[6];
  const float* node_emb = (const float*)d_in[7];
  const float* tod_emb = (const float*)d_in[8];
  const float* dow_emb = (const float*)d_in[9];
  const float* s_qkv_w = (const float*)d_in[10];
  const float* s_qkv_b = (const float*)d_in[11];
  const float* s_proj_w = (const float*)d_in[12];
  const float* s_proj_b = (const float*)d_in[13];
  const float* s_fc1_w = (const float*)d_in[14];
  const float* s_fc1_b = (const float*)d_in[15];
  const float* s_fc2_w = (const float*)d_in[16];
  const float* s_fc2_b = (const float*)d_in[17];
  const float* n_qkv_w = (const float*)d_in[18];
  const float* n_qkv_b = (const float*)d_in[19];
  const float* n_proj_w = (const float*)d_in[20];
  const float* n_proj_b = (const float*)d_in[21];
  const float* n_fc1_w = (const float*)d_in[22];
  const float* n_fc1_b = (const float*)d_in[23];
  const float* n_fc2_w = (const float*)d_in[24];
  const float* n_fc2_b = (const float*)d_in[25];
  const float* w_reg = (const float*)d_in[26];
  const float* b_reg = (const float*)d_in[27];
  (void)reo_all;

  const size_t REX_BYTES = (size_t)NB * TPN * NODES * D * 4;  // 134217728
  if (ws_size < REX_BYTES + 1179648) return;
  float* rex = (float*)d_ws;
  u16* wt = (u16*)((char*)d_ws + REX_BYTES);
  u16* s_qkv_t = wt + 0;
  u16* s_prj_t = wt + 147456;
  u16* s_fc1_t = wt + 196608;
  u16* s_fc2_t = wt + 245760;
  u16* n_qkv_t = wt + 294912;
  u16* n_prj_t = wt + 442368;
  u16* n_fc1_t = wt + 491520;
  u16* n_fc2_t = wt + 540672;

  k_prep<<<(3 * 128 * 384 + 255) / 256, 256, 0, stream>>>(s_qkv_w, s_qkv_t, 128, 384);
  k_prep<<<(3 * 128 * 128 + 255) / 256, 256, 0, stream>>>(s_proj_w, s_prj_t, 128, 128);
  k_prep<<<(3 * 128 * 128 + 255) / 256, 256, 0, stream>>>(s_fc1_w, s_fc1_t, 128, 128);
  k_prep<<<(3 * 128 * 128 + 255) / 256, 256, 0, stream>>>(s_fc2_w, s_fc2_t, 128, 128);
  k_prep<<<(3 * 128 * 384 + 255) / 256, 256, 0, stream>>>(n_qkv_w, n_qkv_t, 128, 384);
  k_prep<<<(3 * 128 * 128 + 255) / 256, 256, 0, stream>>>(n_proj_w, n_prj_t, 128, 128);
  k_prep<<<(3 * 128 * 128 + 255) / 256, 256, 0, stream>>>(n_fc1_w, n_fc1_t, 128, 128);
  k_prep<<<(3 * 128 * 128 + 255) / 256, 256, 0, stream>>>(n_fc2_w, n_fc2_t, 128, 128);

  k_embed<<<NB * TPN * (NODES / 16), 256, 0, stream>>>(
      x, te, reo_parts, w_st, b_st, node_emb, tod_emb, dow_emb, rex);

  for (int l = 0; l < 3; ++l) {
    k_fused<false><<<NB * TPN * (NODES / 256), 1024, 0, stream>>>(
        rex, s_qkv_t + (size_t)l * 49152, s_qkv_b + l * 384,
        s_prj_t + (size_t)l * 16384, s_proj_b + l * 128,
        s_fc1_t + (size_t)l * 16384, s_fc1_b + l * 128,
        s_fc2_t + (size_t)l * 16384, s_fc2_b + l * 128);
    k_fused<true><<<NB * TPN * NPS, 1024, 0, stream>>>(
        rex, n_qkv_t + (size_t)l * 49152, n_qkv_b + l * 384,
        n_prj_t + (size_t)l * 16384, n_proj_b + l * 128,
        n_fc1_t + (size_t)l * 16384, n_fc1_b + l * 128,
        n_fc2_t + (size_t)l * 16384, n_fc2_b + l * 128);
  }

  k_readout<<<NB * (NODES / 64), 256, 0, stream>>>(
      rex, ori_parts, reo_parts, w_reg, b_reg, (float*)d_out);
}

// Round 13
// 1874.899 us; speedup vs baseline: 1.4731x; 1.4731x over previous
//
#include <hip/hip_runtime.h>

#define DEV __device__ __forceinline__
typedef __attribute__((ext_vector_type(8))) short s16x8;
typedef __attribute__((ext_vector_type(4))) float f32x4;
typedef __attribute__((ext_vector_type(4))) int i32x4;
typedef unsigned short u16;

// ---------- constants ----------
#define NB 16      // B
#define TPN 2
#define NODES 8192
#define D 128
#define P 256
#define NPS 32
#define OUT_LEN 12

DEV f32x4 mfma16(s16x8 a, s16x8 b, f32x4 c) {
  return __builtin_amdgcn_mfma_f32_16x16x32_bf16(a, b, c, 0, 0, 0);
}

DEV short f2bf(float f) {
  union { float f; unsigned u; } v; v.f = f;
  unsigned r = v.u + 0x7fffu + ((v.u >> 16) & 1u);
  return (short)(r >> 16);
}
DEV float bf2f(u16 h) {
  union { unsigned u; float f; } v; v.u = ((unsigned)h) << 16; return v.f;
}

// swizzled LDS addressing: 256B-row bf16 buffers, XOR bits 4-6 by row&7
DEV int swz256(int row, int b) { return (row << 8) + (b ^ ((row & 7) << 4)); }
DEV int swz512(int row, int b) { return (row << 9) + (b ^ ((row & 7) << 4)); }

// A-fragment load: lane l -> row = mbase+(l&15), k = kbase+(l>>4)*8 .. +8
DEV s16x8 ldsA(const char* base, int mbase, int kbase, int lane) {
  int row = mbase + (lane & 15);
  int b = (kbase + ((lane >> 4) << 3)) << 1;
  return *(const s16x8*)(base + swz256(row, b));
}

// butterfly reduce across lane bits 0..3
DEV float rowred(float v) {
  v += __shfl_xor(v, 1);
  v += __shfl_xor(v, 2);
  v += __shfl_xor(v, 4);
  v += __shfl_xor(v, 8);
  return v;
}
// reduce across g-groups (lane bits 4,5)
DEV float gred(float v) {
  v += __shfl_xor(v, 16);
  v += __shfl_xor(v, 32);
  return v;
}

// stage one 64-col x 128-k bf16 weight tile (16KB) into LDS, swz256 layout (1024 threads).
DEV void stageW(char* buf, const u16* __restrict__ w, int tid) {
  int col = tid >> 4, kc = tid & 15;
  s16x8 v = *(const s16x8*)(w + col * 128 + kc * 8);
  *(s16x8*)(buf + swz256(col, kc * 16)) = v;
}

// ---------------- weight prep: f32 [3][K][N] -> bf16 [3][N][K] ----------------
__global__ void k_prep(const float* __restrict__ src, u16* __restrict__ dst, int K, int N) {
  int idx = blockIdx.x * 256 + threadIdx.x;
  int total = 3 * K * N;
  if (idx >= total) return;
  int l = idx / (K * N);
  int r = idx - l * K * N;
  int n = r / K;
  int k = r - n * K;
  dst[idx] = (u16)f2bf(src[l * K * N + k * N + n]);
}

// ---------------- embedding (scatter form) ----------------
__global__ __launch_bounds__(256) void k_embed(
    const float* __restrict__ x, const int* __restrict__ te, const int* __restrict__ reo_parts,
    const float* __restrict__ w_st, const float* __restrict__ b_st,
    const float* __restrict__ node_emb, const float* __restrict__ tod_emb,
    const float* __restrict__ dow_emb, float* __restrict__ rex) {
  __shared__ float sx[12][16], s0[12][16], s1[12][16];
  __shared__ int sed[2][16];
  __shared__ int sj[16];
  __shared__ float hb[16][132];
  int gid = blockIdx.x;
  int chunk = gid & 511, bt = gid >> 9;
  int b = bt >> 1, tt = bt & 1;
  int tid = threadIdx.x;
  int nl = tid & 15, c = tid >> 4;
  int n = chunk * 16 + nl;
  if (c < 12) {
    size_t off = ((size_t)(b * 24 + tt * 12 + c)) * NODES + n;
    sx[c][nl] = x[off];
    int2 t2 = *(const int2*)(te + 2 * off);
    s0[c][nl] = (float)t2.x * (1.0f / 288.0f);
    s1[c][nl] = (float)t2.y * (1.0f / 7.0f);
  } else if (c == 12) {
    size_t off = ((size_t)(b * 24 + 22 + tt)) * NODES + n;
    int2 t2 = *(const int2*)(te + 2 * off);
    sed[0][nl] = t2.x;
    sed[1][nl] = t2.y;
  } else if (c == 13) {
    sj[nl] = reo_parts[n];
  }
  __syncthreads();
  int db = c * 8;
  float o[8];
#pragma unroll
  for (int dd = 0; dd < 8; ++dd) {
    int d = db + dd;
    float v;
    if (d < 64) {
      float acc = b_st[d];
      const float* wd = w_st + d * 36;
#pragma unroll
      for (int p = 0; p < 12; ++p)
        acc += sx[p][nl] * wd[p] + s0[p][nl] * wd[12 + p] + s1[p][nl] * wd[24 + p];
      v = acc;
    } else if (d < 80) {
      v = tod_emb[sed[0][nl] * 16 + (d - 64)];
    } else if (d < 96) {
      v = dow_emb[sed[1][nl] * 16 + (d - 80)];
    } else {
      v = node_emb[n * 32 + (d - 96)];
    }
    o[dd] = v;
  }
  *(float4*)&hb[nl][db] = make_float4(o[0], o[1], o[2], o[3]);
  *(float4*)&hb[nl][db + 4] = make_float4(o[4], o[5], o[6], o[7]);
  __syncthreads();
  int row = tid >> 4, cw = tid & 15;
  float4 v0 = *(float4*)&hb[row][cw * 8];
  float4 v1 = *(float4*)&hb[row][cw * 8 + 4];
  float* dst = rex + ((size_t)bt * NODES + sj[row]) * D + cw * 8;
  *(float4*)dst = v0;
  *(float4*)(dst + 4) = v1;
}

// ---------------- fused transformer sublayer pair: 16 waves x 16 tokens ----------------
// LDS-operand discipline: every GEMM operand is re-read from LDS right before its MFMA;
// GEMM outputs go to block-wide bf16 LDS buffers (deltas), residual adds happen in
// per-lane streaming phases (global X + LDS delta). No phase holds >~30 arch regs.
// CROSS=true : token stride 4096, full-256 attention; CROSS=false: stride 128, per-patch.
// LDS map: Kb[0,64K) | VT[64K,128K) | WS[128K,160K).
//   phase A (QKV/attn): Kb=K rows, VT=V^T (scrQ alias pre-V), Pscr in WS.
//   phase B (post-attn): Kb = normAV -> LN2X -> fc2-delta; VT = proj-delta -> gelu.
template <bool CROSS>
__global__ __launch_bounds__(1024, 4) void k_fused(
    float* __restrict__ rex,
    const u16* __restrict__ wqkv, const float* __restrict__ bqkv,
    const u16* __restrict__ wprj, const float* __restrict__ bprj,
    const u16* __restrict__ w1t, const float* __restrict__ b1,
    const u16* __restrict__ w2t, const float* __restrict__ b2) {
  __shared__ __align__(16) char sm[163840];
  char* Kb = sm;
  char* VT = sm + 65536;
  char* WSa = sm + 131072;
  char* WSb = sm + 147456;
  int tid = threadIdx.x;
  int w = tid >> 6, lane = tid & 63;
  int r = lane & 15, g = lane >> 4;
  char* scrQ = sm + 65536 + w * 4096;   // pre-V wave scratch (VT alias)
  char* Pscr = sm + 131072 + w * 1280;  // P tiles (WS alias, attention phase only)

  int sq = blockIdx.x;
  const int TS = CROSS ? (NPS * D) : D;  // token stride in floats
  const size_t TSB = (size_t)TS * 4;
  float* Xblk;
  if (CROSS) {
    int bt = sq >> 5, i = sq & 31;
    Xblk = rex + (size_t)bt * (NODES * D) + i * D;
  } else {
    Xblk = rex + (size_t)sq * (256 * D);
  }
  int myrow = w * 16 + r;
  float* XrowG = (float*)((char*)Xblk + (size_t)myrow * TSB);

  // ---- cooperative X load: 256 rows x 512B contiguous
#pragma unroll
  for (int it = 0; it < 8; ++it) {
    int unit = it * 1024 + tid;
    int row = unit >> 5, col = unit & 31;
    i32x4 v = *(const i32x4*)((const char*)Xblk + (size_t)row * TSB + col * 16);
    *(i32x4*)(sm + (row << 9) + ((col * 16) ^ ((row & 7) << 4))) = v;
  }
  stageW(WSa, wqkv, tid);
  __syncthreads();

  // ---- LN1: transient chunks -> ax fragments only
  s16x8 ax[4];
  {
    float s = 0.f, s2 = 0.f;
#pragma unroll
    for (int kt = 0; kt < 4; ++kt) {
      f32x4 u0 = *(const f32x4*)(sm + (myrow << 9) + ((kt * 128 + g * 32) ^ ((myrow & 7) << 4)));
      f32x4 u1 = *(const f32x4*)(sm + (myrow << 9) + ((kt * 128 + g * 32 + 16) ^ ((myrow & 7) << 4)));
#pragma unroll
      for (int j = 0; j < 4; ++j) { s += u0[j] + u1[j]; s2 += u0[j] * u0[j] + u1[j] * u1[j]; }
    }
    s = gred(s); s2 = gred(s2);
    float m = s * 0.0078125f;
    float rsd = rsqrtf(s2 * 0.0078125f - m * m + 1e-6f);
#pragma unroll
    for (int kt = 0; kt < 4; ++kt) {
      f32x4 u0 = *(const f32x4*)(sm + (myrow << 9) + ((kt * 128 + g * 32) ^ ((myrow & 7) << 4)));
      f32x4 u1 = *(const f32x4*)(sm + (myrow << 9) + ((kt * 128 + g * 32 + 16) ^ ((myrow & 7) << 4)));
      s16x8 o;
#pragma unroll
      for (int j = 0; j < 4; ++j) {
        o[j] = f2bf((u0[j] - m) * rsd);
        o[j + 4] = f2bf((u1[j] - m) * rsd);
      }
      ax[kt] = o;
    }
  }
  __syncthreads();  // X staging consumed; Kb/VT writable

  // ---- QKV: 6 staged 64-col tiles (Q:0-1 -> scrQ, K:2-3 -> Kb, V:4-5 -> VT)
  s16x8 aq[4];
  for (int t = 0; t < 6; ++t) {
    const char* cur = (t & 1) ? WSb : WSa;
    if (t < 5) stageW((t & 1) ? WSa : WSb, wqkv + (size_t)(t + 1) * 8192, tid);
#pragma unroll
    for (int sub = 0; sub < 4; ++sub) {
      int colg = t * 64 + sub * 16 + r;
      f32x4 acc = {0.f, 0.f, 0.f, 0.f};
#pragma unroll
      for (int kt = 0; kt < 4; ++kt)
        acc = mfma16(ax[kt], ldsA(cur, sub * 16, kt * 32, lane), acc);
      float bias = bqkv[colg];
#pragma unroll
      for (int e = 0; e < 4; ++e) {
        float v = acc[e] + bias;
        int tok = w * 16 + g * 4 + e;
        if (t < 2) {
          *(u16*)(scrQ + swz256(g * 4 + e, colg * 2)) = (u16)f2bf(v);
        } else if (t < 4) {
          *(u16*)(Kb + swz256(tok, (colg - 128) * 2)) = (u16)f2bf(v);
        } else {
          *(u16*)(VT + swz512(colg - 256, tok * 2)) = (u16)f2bf(v);
        }
      }
    }
    if (t == 1) {
#pragma unroll
      for (int kt = 0; kt < 4; ++kt) aq[kt] = ldsA(scrQ, 0, kt * 32, lane);
    }
    __syncthreads();
  }

  const float scale = 0.08838834764831845f;
  float sum[4] = {0.f, 0.f, 0.f, 0.f};
  f32x4 av[8];
#pragma unroll
  for (int nt = 0; nt < 8; ++nt) av[nt] = (f32x4){0.f, 0.f, 0.f, 0.f};

  if (CROSS) {
    for (int cc = 0; cc < 8; ++cc) {
#pragma unroll
      for (int sub = 0; sub < 2; ++sub) {
        int kt2 = cc * 2 + sub;
        f32x4 acc = {0.f, 0.f, 0.f, 0.f};
#pragma unroll
        for (int kt = 0; kt < 4; ++kt) {
          s16x8 b = ldsA(Kb, kt2 * 16, kt * 32, lane);
          acc = mfma16(aq[kt], b, acc);
        }
#pragma unroll
        for (int e = 0; e < 4; ++e) {
          float p = __expf(acc[e] * scale);
          sum[e] += p;
          *(u16*)(Pscr + (g * 4 + e) * 80 + (sub * 16 + r) * 2) = (u16)f2bf(p);
        }
      }
      s16x8 ap = *(const s16x8*)(Pscr + r * 80 + g * 16);
#pragma unroll
      for (int nt = 0; nt < 8; ++nt) {
        s16x8 bv = *(const s16x8*)(VT + swz512(nt * 16 + r, (cc * 32 + g * 8) * 2));
        av[nt] = mfma16(ap, bv, av[nt]);
      }
    }
  } else {
    int pw = w >> 1;
#pragma unroll
    for (int sub = 0; sub < 2; ++sub) {
      f32x4 acc = {0.f, 0.f, 0.f, 0.f};
#pragma unroll
      for (int kt = 0; kt < 4; ++kt) {
        s16x8 b = ldsA(Kb, pw * 32 + sub * 16, kt * 32, lane);
        acc = mfma16(aq[kt], b, acc);
      }
#pragma unroll
      for (int e = 0; e < 4; ++e) {
        float p = __expf(acc[e] * scale);
        sum[e] += p;
        *(u16*)(Pscr + (g * 4 + e) * 80 + (sub * 16 + r) * 2) = (u16)f2bf(p);
      }
    }
    s16x8 ap = *(const s16x8*)(Pscr + r * 80 + g * 16);
#pragma unroll
    for (int nt = 0; nt < 8; ++nt) {
      s16x8 bv = *(const s16x8*)(VT + swz512(nt * 16 + r, (pw * 32 + g * 8) * 2));
      f32x4 z = {0.f, 0.f, 0.f, 0.f};
      av[nt] = mfma16(ap, bv, z);
    }
  }
#pragma unroll
  for (int e = 0; e < 4; ++e) sum[e] = rowred(sum[e]);
  __syncthreads();  // Kb/VT attention reads done -> both regions reusable

  // ---- normalize AV -> Kb (bf16, block layout [tok])
  {
    float rinv[4];
#pragma unroll
    for (int e = 0; e < 4; ++e) rinv[e] = 1.0f / sum[e];
#pragma unroll
    for (int nt = 0; nt < 8; ++nt)
#pragma unroll
      for (int e = 0; e < 4; ++e)
        *(u16*)(Kb + swz256(w * 16 + g * 4 + e, (nt * 16 + r) * 2)) =
            (u16)f2bf(av[nt][e] * rinv[e]);
  }

  // ---- proj: operands from Kb per tile; out bf16 delta -> VT[tok]
  stageW(WSa, wprj, tid);
  __syncthreads();
#pragma unroll
  for (int t = 0; t < 2; ++t) {
    const char* cur = t ? WSb : WSa;
    if (t == 0) stageW(WSb, wprj + 8192, tid);
#pragma unroll
    for (int sub = 0; sub < 4; ++sub) {
      int colg = t * 64 + sub * 16 + r;
      f32x4 acc = {0.f, 0.f, 0.f, 0.f};
#pragma unroll
      for (int kt = 0; kt < 4; ++kt)
        acc = mfma16(ldsA(Kb, w * 16, kt * 32, lane), ldsA(cur, sub * 16, kt * 32, lane), acc);
      float bias = bprj[colg];
#pragma unroll
      for (int e = 0; e < 4; ++e)
        *(u16*)(VT + swz256(w * 16 + g * 4 + e, colg * 2)) = (u16)f2bf(acc[e] + bias);
    }
    __syncthreads();
  }

  // ---- residual add + LN2 (streaming, per-lane): X' = X + delta -> global; LN2X -> Kb
  {
    float s = 0.f, s2 = 0.f;
#pragma unroll
    for (int kt = 0; kt < 4; ++kt) {
      float4 a = *(const float4*)(XrowG + kt * 32 + g * 8);
      float4 b = *(const float4*)(XrowG + kt * 32 + g * 8 + 4);
      s16x8 d = *(const s16x8*)(VT + swz256(myrow, (kt * 32 + g * 8) * 2));
      float v0 = a.x + bf2f((u16)d[0]), v1 = a.y + bf2f((u16)d[1]);
      float v2 = a.z + bf2f((u16)d[2]), v3 = a.w + bf2f((u16)d[3]);
      float v4 = b.x + bf2f((u16)d[4]), v5 = b.y + bf2f((u16)d[5]);
      float v6 = b.z + bf2f((u16)d[6]), v7 = b.w + bf2f((u16)d[7]);
      *(float4*)(XrowG + kt * 32 + g * 8) = make_float4(v0, v1, v2, v3);
      *(float4*)(XrowG + kt * 32 + g * 8 + 4) = make_float4(v4, v5, v6, v7);
      s += v0 + v1 + v2 + v3 + v4 + v5 + v6 + v7;
      s2 += v0 * v0 + v1 * v1 + v2 * v2 + v3 * v3 + v4 * v4 + v5 * v5 + v6 * v6 + v7 * v7;
    }
    s = gred(s); s2 = gred(s2);
    float m = s * 0.0078125f;
    float rsd = rsqrtf(s2 * 0.0078125f - m * m + 1e-6f);
#pragma unroll
    for (int kt = 0; kt < 4; ++kt) {
      float4 a = *(const float4*)(XrowG + kt * 32 + g * 8);
      float4 b = *(const float4*)(XrowG + kt * 32 + g * 8 + 4);
      s16x8 o;
      o[0] = f2bf((a.x - m) * rsd); o[1] = f2bf((a.y - m) * rsd);
      o[2] = f2bf((a.z - m) * rsd); o[3] = f2bf((a.w - m) * rsd);
      o[4] = f2bf((b.x - m) * rsd); o[5] = f2bf((b.y - m) * rsd);
      o[6] = f2bf((b.z - m) * rsd); o[7] = f2bf((b.w - m) * rsd);
      *(s16x8*)(Kb + swz256(myrow, (kt * 32 + g * 8) * 2)) = o;
    }
  }

  // ---- fc1 + gelu: operands from Kb per tile -> VT (gelu bf16)
  stageW(WSa, w1t, tid);
  __syncthreads();
#pragma unroll
  for (int t = 0; t < 2; ++t) {
    const char* cur = t ? WSb : WSa;
    if (t == 0) stageW(WSb, w1t + 8192, tid);
#pragma unroll
    for (int sub = 0; sub < 4; ++sub) {
      int colg = t * 64 + sub * 16 + r;
      f32x4 acc = {0.f, 0.f, 0.f, 0.f};
#pragma unroll
      for (int kt = 0; kt < 4; ++kt)
        acc = mfma16(ldsA(Kb, w * 16, kt * 32, lane), ldsA(cur, sub * 16, kt * 32, lane), acc);
      float bias = b1[colg];
#pragma unroll
      for (int e = 0; e < 4; ++e) {
        float v0 = acc[e] + bias;
        v0 = 0.5f * v0 * (1.0f + erff(v0 * 0.70710678118654752f));
        *(u16*)(VT + swz256(w * 16 + g * 4 + e, colg * 2)) = (u16)f2bf(v0);
      }
    }
    __syncthreads();
  }

  // ---- fc2: operands from VT per tile -> Kb (delta2 bf16)
  stageW(WSa, w2t, tid);
  __syncthreads();
#pragma unroll
  for (int t = 0; t < 2; ++t) {
    const char* cur = t ? WSb : WSa;
    if (t == 0) stageW(WSb, w2t + 8192, tid);
#pragma unroll
    for (int sub = 0; sub < 4; ++sub) {
      int colg = t * 64 + sub * 16 + r;
      f32x4 acc = {0.f, 0.f, 0.f, 0.f};
#pragma unroll
      for (int kt = 0; kt < 4; ++kt)
        acc = mfma16(ldsA(VT, w * 16, kt * 32, lane), ldsA(cur, sub * 16, kt * 32, lane), acc);
      float bias = b2[colg];
#pragma unroll
      for (int e = 0; e < 4; ++e)
        *(u16*)(Kb + swz256(w * 16 + g * 4 + e, colg * 2)) = (u16)f2bf(acc[e] + bias);
    }
    if (t == 0) __syncthreads();
  }

  // ---- final residual (streaming, per-lane): X'' = X' + delta2 -> global
#pragma unroll
  for (int kt = 0; kt < 4; ++kt) {
    float4 a = *(const float4*)(XrowG + kt * 32 + g * 8);
    float4 b = *(const float4*)(XrowG + kt * 32 + g * 8 + 4);
    s16x8 d = *(const s16x8*)(Kb + swz256(myrow, (kt * 32 + g * 8) * 2));
    *(float4*)(XrowG + kt * 32 + g * 8) = make_float4(
        a.x + bf2f((u16)d[0]), a.y + bf2f((u16)d[1]),
        a.z + bf2f((u16)d[2]), a.w + bf2f((u16)d[3]));
    *(float4*)(XrowG + kt * 32 + g * 8 + 4) = make_float4(
        b.x + bf2f((u16)d[4]), b.y + bf2f((u16)d[5]),
        b.z + bf2f((u16)d[6]), b.w + bf2f((u16)d[7]));
  }
}

// ---------------- readout ----------------
__global__ __launch_bounds__(256) void k_readout(
    const float* __restrict__ rex, const int* __restrict__ ori_idx,
    const int* __restrict__ reo_idx, const float* __restrict__ w_reg,
    const float* __restrict__ b_reg, float* __restrict__ out) {
  __shared__ float wl[3072];
  for (int i2 = threadIdx.x; i2 < 3072; i2 += 256) wl[i2] = w_reg[i2];
  __syncthreads();
  int b = blockIdx.x >> 7;
  int chunk = blockIdx.x & 127;
  int m = chunk * 64 + (threadIdx.x >> 2);
  int q = threadIdx.x & 3;
  int nOut = ori_idx[m];
  int j = reo_idx[m];
  int t = q >> 1;
  const float* src = rex + ((size_t)(b * 2 + t) * NODES + j) * D + (q & 1) * 64;
  float acc[12] = {0.f, 0.f, 0.f, 0.f, 0.f, 0.f, 0.f, 0.f, 0.f, 0.f, 0.f, 0.f};
#pragma unroll
  for (int k = 0; k < 64; k += 4) {
    float4 v = *(const float4*)(src + k);
#pragma unroll
    for (int o = 0; o < 12; ++o) {
      float4 wv = *(const float4*)(&wl[o * 256 + q * 64 + k]);
      acc[o] += v.x * wv.x + v.y * wv.y + v.z * wv.z + v.w * wv.w;
    }
  }
#pragma unroll
  for (int o = 0; o < 12; ++o) {
    acc[o] += __shfl_xor(acc[o], 1);
    acc[o] += __shfl_xor(acc[o], 2);
  }
  if (q == 0) {
#pragma unroll
    for (int o = 0; o < 12; ++o)
      out[((size_t)b * 12 + o) * NODES + nOut] = acc[o] + b_reg[o];
  }
}

// ---------------- host ----------------
extern "C" void kernel_launch(void* const* d_in, const int* in_sizes, int n_in,
                              void* d_out, int out_size, void* d_ws, size_t ws_size,
                              hipStream_t stream) {
  (void)in_sizes; (void)n_in; (void)out_size;
  const float* x = (const float*)d_in[0];
  const int* te = (const int*)d_in[1];
  const int* reo_all = (const int*)d_in[2];
  const int* ori_parts = (const int*)d_in[3];
  const int* reo_parts = (const int*)d_in[4];
  const float* w_st = (const float*)d_in[5];
  const float* b_st = (const float*)d_in[6];
  const float* node_emb = (const float*)d_in[7];
  const float* tod_emb = (const float*)d_in[8];
  const float* dow_emb = (const float*)d_in[9];
  const float* s_qkv_w = (const float*)d_in[10];
  const float* s_qkv_b = (const float*)d_in[11];
  const float* s_proj_w = (const float*)d_in[12];
  const float* s_proj_b = (const float*)d_in[13];
  const float* s_fc1_w = (const float*)d_in[14];
  const float* s_fc1_b = (const float*)d_in[15];
  const float* s_fc2_w = (const float*)d_in[16];
  const float* s_fc2_b = (const float*)d_in[17];
  const float* n_qkv_w = (const float*)d_in[18];
  const float* n_qkv_b = (const float*)d_in[19];
  const float* n_proj_w = (const float*)d_in[20];
  const float* n_proj_b = (const float*)d_in[21];
  const float* n_fc1_w = (const float*)d_in[22];
  const float* n_fc1_b = (const float*)d_in[23];
  const float* n_fc2_w = (const float*)d_in[24];
  const float* n_fc2_b = (const float*)d_in[25];
  const float* w_reg = (const float*)d_in[26];
  const float* b_reg = (const float*)d_in[27];
  (void)reo_all;

  const size_t REX_BYTES = (size_t)NB * TPN * NODES * D * 4;  // 134217728
  if (ws_size < REX_BYTES + 1179648) return;
  float* rex = (float*)d_ws;
  u16* wt = (u16*)((char*)d_ws + REX_BYTES);
  u16* s_qkv_t = wt + 0;
  u16* s_prj_t = wt + 147456;
  u16* s_fc1_t = wt + 196608;
  u16* s_fc2_t = wt + 245760;
  u16* n_qkv_t = wt + 294912;
  u16* n_prj_t = wt + 442368;
  u16* n_fc1_t = wt + 491520;
  u16* n_fc2_t = wt + 540672;

  k_prep<<<(3 * 128 * 384 + 255) / 256, 256, 0, stream>>>(s_qkv_w, s_qkv_t, 128, 384);
  k_prep<<<(3 * 128 * 128 + 255) / 256, 256, 0, stream>>>(s_proj_w, s_prj_t, 128, 128);
  k_prep<<<(3 * 128 * 128 + 255) / 256, 256, 0, stream>>>(s_fc1_w, s_fc1_t, 128, 128);
  k_prep<<<(3 * 128 * 128 + 255) / 256, 256, 0, stream>>>(s_fc2_w, s_fc2_t, 128, 128);
  k_prep<<<(3 * 128 * 384 + 255) / 256, 256, 0, stream>>>(n_qkv_w, n_qkv_t, 128, 384);
  k_prep<<<(3 * 128 * 128 + 255) / 256, 256, 0, stream>>>(n_proj_w, n_prj_t, 128, 128);
  k_prep<<<(3 * 128 * 128 + 255) / 256, 256, 0, stream>>>(n_fc1_w, n_fc1_t, 128, 128);
  k_prep<<<(3 * 128 * 128 + 255) / 256, 256, 0, stream>>>(n_fc2_w, n_fc2_t, 128, 128);

  k_embed<<<NB * TPN * (NODES / 16), 256, 0, stream>>>(
      x, te, reo_parts, w_st, b_st, node_emb, tod_emb, dow_emb, rex);

  for (int l = 0; l < 3; ++l) {
    k_fused<false><<<NB * TPN * (NODES / 256), 1024, 0, stream>>>(
        rex, s_qkv_t + (size_t)l * 49152, s_qkv_b + l * 384,
        s_prj_t + (size_t)l * 16384, s_proj_b + l * 128,
        s_fc1_t + (size_t)l * 16384, s_fc1_b + l * 128,
        s_fc2_t + (size_t)l * 16384, s_fc2_b + l * 128);
    k_fused<true><<<NB * TPN * NPS, 1024, 0, stream>>>(
        rex, n_qkv_t + (size_t)l * 49152, n_qkv_b + l * 384,
        n_prj_t + (size_t)l * 16384, n_proj_b + l * 128,
        n_fc1_t + (size_t)l * 16384, n_fc1_b + l * 128,
        n_fc2_t + (size_t)l * 16384, n_fc2_b + l * 128);
  }

  k_readout<<<NB * (NODES / 64), 256, 0, stream>>>(
      rex, ori_parts, reo_parts, w_reg, b_reg, (float*)d_out);
}

// Round 14
// 1786.493 us; speedup vs baseline: 1.5460x; 1.0495x over previous
//
#include <hip/hip_runtime.h>
#include <hip/hip_bf16.h>

#define DEV __device__ __forceinline__
typedef __attribute__((ext_vector_type(8))) short s16x8;
typedef __attribute__((ext_vector_type(4))) float f32x4;
typedef __attribute__((ext_vector_type(4))) int i32x4;
typedef unsigned short u16;

// ---------- constants ----------
#define NB 16      // B
#define TPN 2
#define NODES 8192
#define D 128
#define P 256
#define NPS 32
#define OUT_LEN 12

DEV f32x4 mfma16(s16x8 a, s16x8 b, f32x4 c) {
  return __builtin_amdgcn_mfma_f32_16x16x32_bf16(a, b, c, 0, 0, 0);
}

DEV u16 f2bf(float f) {
  __hip_bfloat16 h = __float2bfloat16(f);
  u16 u;
  __builtin_memcpy(&u, &h, 2);
  return u;
}
DEV float bf2f(u16 h) {
  union { unsigned u; float f; } v; v.u = ((unsigned)h) << 16; return v.f;
}

// swizzled LDS addressing: 256B-row bf16 buffers, XOR bits 4-6 by row&7
DEV int swz256(int row, int b) { return (row << 8) + (b ^ ((row & 7) << 4)); }
DEV int swz512(int row, int b) { return (row << 9) + (b ^ ((row & 7) << 4)); }

// A-fragment load: lane l -> row = mbase+(l&15), k = kbase+(l>>4)*8 .. +8
DEV s16x8 ldsA(const char* base, int mbase, int kbase, int lane) {
  int row = mbase + (lane & 15);
  int b = (kbase + ((lane >> 4) << 3)) << 1;
  return *(const s16x8*)(base + swz256(row, b));
}

// butterfly reduce across lane bits 0..3
DEV float rowred(float v) {
  v += __shfl_xor(v, 1);
  v += __shfl_xor(v, 2);
  v += __shfl_xor(v, 4);
  v += __shfl_xor(v, 8);
  return v;
}
// reduce across g-groups (lane bits 4,5)
DEV float gred(float v) {
  v += __shfl_xor(v, 16);
  v += __shfl_xor(v, 32);
  return v;
}

// stage one 64-col x 128-k bf16 weight tile (16KB) into LDS, swz256 layout (1024 threads).
DEV void stageW(char* buf, const u16* __restrict__ w, int tid) {
  int col = tid >> 4, kc = tid & 15;
  s16x8 v = *(const s16x8*)(w + col * 128 + kc * 8);
  *(s16x8*)(buf + swz256(col, kc * 16)) = v;
}

// ---------------- weight prep: f32 [3][K][N] -> bf16 [3][N][K] ----------------
__global__ void k_prep(const float* __restrict__ src, u16* __restrict__ dst, int K, int N) {
  int idx = blockIdx.x * 256 + threadIdx.x;
  int total = 3 * K * N;
  if (idx >= total) return;
  int l = idx / (K * N);
  int r = idx - l * K * N;
  int n = r / K;
  int k = r - n * K;
  dst[idx] = f2bf(src[l * K * N + k * N + n]);
}

// ---------------- embedding (scatter form) ----------------
__global__ __launch_bounds__(256) void k_embed(
    const float* __restrict__ x, const int* __restrict__ te, const int* __restrict__ reo_parts,
    const float* __restrict__ w_st, const float* __restrict__ b_st,
    const float* __restrict__ node_emb, const float* __restrict__ tod_emb,
    const float* __restrict__ dow_emb, float* __restrict__ rex) {
  __shared__ float sx[12][16], s0[12][16], s1[12][16];
  __shared__ int sed[2][16];
  __shared__ int sj[16];
  __shared__ float hb[16][132];
  int gid = blockIdx.x;
  int chunk = gid & 511, bt = gid >> 9;
  int b = bt >> 1, tt = bt & 1;
  int tid = threadIdx.x;
  int nl = tid & 15, c = tid >> 4;
  int n = chunk * 16 + nl;
  if (c < 12) {
    size_t off = ((size_t)(b * 24 + tt * 12 + c)) * NODES + n;
    sx[c][nl] = x[off];
    int2 t2 = *(const int2*)(te + 2 * off);
    s0[c][nl] = (float)t2.x * (1.0f / 288.0f);
    s1[c][nl] = (float)t2.y * (1.0f / 7.0f);
  } else if (c == 12) {
    size_t off = ((size_t)(b * 24 + 22 + tt)) * NODES + n;
    int2 t2 = *(const int2*)(te + 2 * off);
    sed[0][nl] = t2.x;
    sed[1][nl] = t2.y;
  } else if (c == 13) {
    sj[nl] = reo_parts[n];
  }
  __syncthreads();
  int db = c * 8;
  float o[8];
#pragma unroll
  for (int dd = 0; dd < 8; ++dd) {
    int d = db + dd;
    float v;
    if (d < 64) {
      float acc = b_st[d];
      const float* wd = w_st + d * 36;
#pragma unroll
      for (int p = 0; p < 12; ++p)
        acc += sx[p][nl] * wd[p] + s0[p][nl] * wd[12 + p] + s1[p][nl] * wd[24 + p];
      v = acc;
    } else if (d < 80) {
      v = tod_emb[sed[0][nl] * 16 + (d - 64)];
    } else if (d < 96) {
      v = dow_emb[sed[1][nl] * 16 + (d - 80)];
    } else {
      v = node_emb[n * 32 + (d - 96)];
    }
    o[dd] = v;
  }
  *(float4*)&hb[nl][db] = make_float4(o[0], o[1], o[2], o[3]);
  *(float4*)&hb[nl][db + 4] = make_float4(o[4], o[5], o[6], o[7]);
  __syncthreads();
  int row = tid >> 4, cw = tid & 15;
  float4 v0 = *(float4*)&hb[row][cw * 8];
  float4 v1 = *(float4*)&hb[row][cw * 8 + 4];
  float* dst = rex + ((size_t)bt * NODES + sj[row]) * D + cw * 8;
  *(float4*)dst = v0;
  *(float4*)(dst + 4) = v1;
}

// ---------------- fused transformer sublayer pair: 16 waves x 16 tokens ----------------
// Phase B is wave-row-private: GEMM outputs go to bf16 LDS buffers indexed by the wave's
// own token rows; barriers exist only around weight staging. X is written to global ONCE
// (X'' = X + delta12 at the end); LN2 is computed streaming from X + delta1.
// CROSS=true : token stride 4096, full-256 attention; CROSS=false: stride 128, per-patch.
// LDS map: Kb[0,64K) | VT[64K,128K) | WS[128K,160K).
//   phase A (QKV/attn): Kb=K rows, VT=V^T (scrQ alias pre-V), Pscr in WS.
//   phase B: Kb = normAV -> LN2X -> gelu (in-place); VT = delta1 -> delta12.
template <bool CROSS>
__global__ __launch_bounds__(1024, 4) void k_fused(
    float* __restrict__ rex,
    const u16* __restrict__ wqkv, const float* __restrict__ bqkv,
    const u16* __restrict__ wprj, const float* __restrict__ bprj,
    const u16* __restrict__ w1t, const float* __restrict__ b1,
    const u16* __restrict__ w2t, const float* __restrict__ b2) {
  __shared__ __align__(16) char sm[163840];
  char* Kb = sm;
  char* VT = sm + 65536;
  char* WSa = sm + 131072;
  char* WSb = sm + 147456;
  int tid = threadIdx.x;
  int w = tid >> 6, lane = tid & 63;
  int r = lane & 15, g = lane >> 4;
  char* scrQ = sm + 65536 + w * 4096;   // pre-V wave scratch (VT alias)
  char* Pscr = sm + 131072 + w * 1280;  // P tiles (WS alias, attention phase only)

  int sq = blockIdx.x;
  const int TS = CROSS ? (NPS * D) : D;  // token stride in floats
  const size_t TSB = (size_t)TS * 4;
  float* Xblk;
  if (CROSS) {
    int bt = sq >> 5, i = sq & 31;
    Xblk = rex + (size_t)bt * (NODES * D) + i * D;
  } else {
    Xblk = rex + (size_t)sq * (256 * D);
  }
  int myrow = w * 16 + r;
  float* XrowG = (float*)((char*)Xblk + (size_t)myrow * TSB);

  // ---- cooperative X load: 256 rows x 512B contiguous
#pragma unroll
  for (int it = 0; it < 8; ++it) {
    int unit = it * 1024 + tid;
    int row = unit >> 5, col = unit & 31;
    i32x4 v = *(const i32x4*)((const char*)Xblk + (size_t)row * TSB + col * 16);
    *(i32x4*)(sm + (row << 9) + ((col * 16) ^ ((row & 7) << 4))) = v;
  }
  stageW(WSa, wqkv, tid);
  __syncthreads();

  // ---- LN1: transient chunks -> ax fragments only
  s16x8 ax[4];
  {
    float s = 0.f, s2 = 0.f;
#pragma unroll
    for (int kt = 0; kt < 4; ++kt) {
      f32x4 u0 = *(const f32x4*)(sm + (myrow << 9) + ((kt * 128 + g * 32) ^ ((myrow & 7) << 4)));
      f32x4 u1 = *(const f32x4*)(sm + (myrow << 9) + ((kt * 128 + g * 32 + 16) ^ ((myrow & 7) << 4)));
#pragma unroll
      for (int j = 0; j < 4; ++j) { s += u0[j] + u1[j]; s2 += u0[j] * u0[j] + u1[j] * u1[j]; }
    }
    s = gred(s); s2 = gred(s2);
    float m = s * 0.0078125f;
    float rsd = rsqrtf(s2 * 0.0078125f - m * m + 1e-6f);
#pragma unroll
    for (int kt = 0; kt < 4; ++kt) {
      f32x4 u0 = *(const f32x4*)(sm + (myrow << 9) + ((kt * 128 + g * 32) ^ ((myrow & 7) << 4)));
      f32x4 u1 = *(const f32x4*)(sm + (myrow << 9) + ((kt * 128 + g * 32 + 16) ^ ((myrow & 7) << 4)));
      s16x8 o;
#pragma unroll
      for (int j = 0; j < 4; ++j) {
        o[j] = (short)f2bf((u0[j] - m) * rsd);
        o[j + 4] = (short)f2bf((u1[j] - m) * rsd);
      }
      ax[kt] = o;
    }
  }
  __syncthreads();  // X staging consumed; Kb/VT writable

  // ---- QKV: 6 staged 64-col tiles (Q:0-1 -> scrQ, K:2-3 -> Kb, V:4-5 -> VT)
  s16x8 aq[4];
  for (int t = 0; t < 6; ++t) {
    const char* cur = (t & 1) ? WSb : WSa;
    if (t < 5) stageW((t & 1) ? WSa : WSb, wqkv + (size_t)(t + 1) * 8192, tid);
#pragma unroll
    for (int sub = 0; sub < 4; ++sub) {
      int colg = t * 64 + sub * 16 + r;
      f32x4 acc = {0.f, 0.f, 0.f, 0.f};
#pragma unroll
      for (int kt = 0; kt < 4; ++kt)
        acc = mfma16(ax[kt], ldsA(cur, sub * 16, kt * 32, lane), acc);
      float bias = bqkv[colg];
#pragma unroll
      for (int e = 0; e < 4; ++e) {
        float v = acc[e] + bias;
        int tok = w * 16 + g * 4 + e;
        if (t < 2) {
          *(u16*)(scrQ + swz256(g * 4 + e, colg * 2)) = f2bf(v);
        } else if (t < 4) {
          *(u16*)(Kb + swz256(tok, (colg - 128) * 2)) = f2bf(v);
        } else {
          *(u16*)(VT + swz512(colg - 256, tok * 2)) = f2bf(v);
        }
      }
    }
    if (t == 1) {
#pragma unroll
      for (int kt = 0; kt < 4; ++kt) aq[kt] = ldsA(scrQ, 0, kt * 32, lane);
    }
    __syncthreads();
  }

  const float scale = 0.08838834764831845f;
  float sum[4] = {0.f, 0.f, 0.f, 0.f};
  f32x4 av[8];
#pragma unroll
  for (int nt = 0; nt < 8; ++nt) av[nt] = (f32x4){0.f, 0.f, 0.f, 0.f};

  if (CROSS) {
    for (int cc = 0; cc < 8; ++cc) {
#pragma unroll
      for (int sub = 0; sub < 2; ++sub) {
        int kt2 = cc * 2 + sub;
        f32x4 acc = {0.f, 0.f, 0.f, 0.f};
#pragma unroll
        for (int kt = 0; kt < 4; ++kt) {
          s16x8 b = ldsA(Kb, kt2 * 16, kt * 32, lane);
          acc = mfma16(aq[kt], b, acc);
        }
#pragma unroll
        for (int e = 0; e < 4; ++e) {
          float p = __expf(acc[e] * scale);
          sum[e] += p;
          *(u16*)(Pscr + (g * 4 + e) * 80 + (sub * 16 + r) * 2) = f2bf(p);
        }
      }
      s16x8 ap = *(const s16x8*)(Pscr + r * 80 + g * 16);
#pragma unroll
      for (int nt = 0; nt < 8; ++nt) {
        s16x8 bv = *(const s16x8*)(VT + swz512(nt * 16 + r, (cc * 32 + g * 8) * 2));
        av[nt] = mfma16(ap, bv, av[nt]);
      }
    }
  } else {
    int pw = w >> 1;
#pragma unroll
    for (int sub = 0; sub < 2; ++sub) {
      f32x4 acc = {0.f, 0.f, 0.f, 0.f};
#pragma unroll
      for (int kt = 0; kt < 4; ++kt) {
        s16x8 b = ldsA(Kb, pw * 32 + sub * 16, kt * 32, lane);
        acc = mfma16(aq[kt], b, acc);
      }
#pragma unroll
      for (int e = 0; e < 4; ++e) {
        float p = __expf(acc[e] * scale);
        sum[e] += p;
        *(u16*)(Pscr + (g * 4 + e) * 80 + (sub * 16 + r) * 2) = f2bf(p);
      }
    }
    s16x8 ap = *(const s16x8*)(Pscr + r * 80 + g * 16);
#pragma unroll
    for (int nt = 0; nt < 8; ++nt) {
      s16x8 bv = *(const s16x8*)(VT + swz512(nt * 16 + r, (pw * 32 + g * 8) * 2));
      f32x4 z = {0.f, 0.f, 0.f, 0.f};
      av[nt] = mfma16(ap, bv, z);
    }
  }
#pragma unroll
  for (int e = 0; e < 4; ++e) sum[e] = rowred(sum[e]);
  __syncthreads();  // Kb/VT attention reads done -> both regions reusable; WS (Pscr) free

  // ---- normAV -> Kb own rows; stage full Wprj (32KB)
  {
    float rinv[4];
#pragma unroll
    for (int e = 0; e < 4; ++e) rinv[e] = 1.0f / sum[e];
#pragma unroll
    for (int nt = 0; nt < 8; ++nt)
#pragma unroll
      for (int e = 0; e < 4; ++e)
        *(u16*)(Kb + swz256(w * 16 + g * 4 + e, (nt * 16 + r) * 2)) =
            f2bf(av[nt][e] * rinv[e]);
  }
  stageW(WSa, wprj, tid);
  stageW(WSb, wprj + 8192, tid);
  __syncthreads();

  // ---- proj: reg-accumulated, delta1 bf16 -> VT own rows
  {
    f32x4 accp[2][4];
#pragma unroll
    for (int t = 0; t < 2; ++t)
#pragma unroll
      for (int sub = 0; sub < 4; ++sub) {
        f32x4 acc = {0.f, 0.f, 0.f, 0.f};
#pragma unroll
        for (int kt = 0; kt < 4; ++kt)
          acc = mfma16(ldsA(Kb, w * 16, kt * 32, lane),
                       ldsA(t ? WSb : WSa, sub * 16, kt * 32, lane), acc);
        accp[t][sub] = acc;
      }
#pragma unroll
    for (int t = 0; t < 2; ++t)
#pragma unroll
      for (int sub = 0; sub < 4; ++sub) {
        int colg = t * 64 + sub * 16 + r;
        float bias = bprj[colg];
#pragma unroll
        for (int e = 0; e < 4; ++e)
          *(u16*)(VT + swz256(w * 16 + g * 4 + e, colg * 2)) = f2bf(accp[t][sub][e] + bias);
      }
  }
  __syncthreads();  // WS consumers done -> w1 staging allowed

  // ---- streaming LN2: X' = X + delta1 (NOT written to global); LN2X bf16 -> Kb own rows
  {
    float s = 0.f, s2 = 0.f;
#pragma unroll
    for (int kt = 0; kt < 4; ++kt) {
      float4 a = *(const float4*)(XrowG + kt * 32 + g * 8);
      float4 b = *(const float4*)(XrowG + kt * 32 + g * 8 + 4);
      s16x8 d = *(const s16x8*)(VT + swz256(myrow, (kt * 32 + g * 8) * 2));
      float v0 = a.x + bf2f((u16)d[0]), v1 = a.y + bf2f((u16)d[1]);
      float v2 = a.z + bf2f((u16)d[2]), v3 = a.w + bf2f((u16)d[3]);
      float v4 = b.x + bf2f((u16)d[4]), v5 = b.y + bf2f((u16)d[5]);
      float v6 = b.z + bf2f((u16)d[6]), v7 = b.w + bf2f((u16)d[7]);
      s += v0 + v1 + v2 + v3 + v4 + v5 + v6 + v7;
      s2 += v0 * v0 + v1 * v1 + v2 * v2 + v3 * v3 + v4 * v4 + v5 * v5 + v6 * v6 + v7 * v7;
    }
    s = gred(s); s2 = gred(s2);
    float m = s * 0.0078125f;
    float rsd = rsqrtf(s2 * 0.0078125f - m * m + 1e-6f);
#pragma unroll
    for (int kt = 0; kt < 4; ++kt) {
      float4 a = *(const float4*)(XrowG + kt * 32 + g * 8);
      float4 b = *(const float4*)(XrowG + kt * 32 + g * 8 + 4);
      s16x8 d = *(const s16x8*)(VT + swz256(myrow, (kt * 32 + g * 8) * 2));
      s16x8 o;
      o[0] = (short)f2bf((a.x + bf2f((u16)d[0]) - m) * rsd);
      o[1] = (short)f2bf((a.y + bf2f((u16)d[1]) - m) * rsd);
      o[2] = (short)f2bf((a.z + bf2f((u16)d[2]) - m) * rsd);
      o[3] = (short)f2bf((a.w + bf2f((u16)d[3]) - m) * rsd);
      o[4] = (short)f2bf((b.x + bf2f((u16)d[4]) - m) * rsd);
      o[5] = (short)f2bf((b.y + bf2f((u16)d[5]) - m) * rsd);
      o[6] = (short)f2bf((b.z + bf2f((u16)d[6]) - m) * rsd);
      o[7] = (short)f2bf((b.w + bf2f((u16)d[7]) - m) * rsd);
      *(s16x8*)(Kb + swz256(myrow, (kt * 32 + g * 8) * 2)) = o;
    }
  }
  stageW(WSa, w1t, tid);
  stageW(WSb, w1t + 8192, tid);
  __syncthreads();

  // ---- fc1: reg-accumulated; gelu in-place over Kb own rows
  {
    f32x4 acc1[2][4];
#pragma unroll
    for (int t = 0; t < 2; ++t)
#pragma unroll
      for (int sub = 0; sub < 4; ++sub) {
        f32x4 acc = {0.f, 0.f, 0.f, 0.f};
#pragma unroll
        for (int kt = 0; kt < 4; ++kt)
          acc = mfma16(ldsA(Kb, w * 16, kt * 32, lane),
                       ldsA(t ? WSb : WSa, sub * 16, kt * 32, lane), acc);
        acc1[t][sub] = acc;
      }
#pragma unroll
    for (int t = 0; t < 2; ++t)
#pragma unroll
      for (int sub = 0; sub < 4; ++sub) {
        int colg = t * 64 + sub * 16 + r;
        float bias = b1[colg];
#pragma unroll
        for (int e = 0; e < 4; ++e) {
          float v0 = acc1[t][sub][e] + bias;
          v0 = 0.5f * v0 * (1.0f + erff(v0 * 0.70710678118654752f));
          *(u16*)(Kb + swz256(w * 16 + g * 4 + e, colg * 2)) = f2bf(v0);
        }
      }
  }
  __syncthreads();  // WS consumers done -> w2 staging allowed
  stageW(WSa, w2t, tid);
  stageW(WSb, w2t + 8192, tid);
  __syncthreads();

  // ---- fc2: reg-accumulated; delta12 = delta1 + delta2 in-place in VT own rows
  {
    f32x4 acc2[2][4];
#pragma unroll
    for (int t = 0; t < 2; ++t)
#pragma unroll
      for (int sub = 0; sub < 4; ++sub) {
        f32x4 acc = {0.f, 0.f, 0.f, 0.f};
#pragma unroll
        for (int kt = 0; kt < 4; ++kt)
          acc = mfma16(ldsA(Kb, w * 16, kt * 32, lane),
                       ldsA(t ? WSb : WSa, sub * 16, kt * 32, lane), acc);
        acc2[t][sub] = acc;
      }
#pragma unroll
    for (int t = 0; t < 2; ++t)
#pragma unroll
      for (int sub = 0; sub < 4; ++sub) {
        int colg = t * 64 + sub * 16 + r;
        float bias = b2[colg];
#pragma unroll
        for (int e = 0; e < 4; ++e) {
          int row = w * 16 + g * 4 + e;
          u16 d1 = *(u16*)(VT + swz256(row, colg * 2));
          *(u16*)(VT + swz256(row, colg * 2)) =
              f2bf(acc2[t][sub][e] + bias + bf2f(d1));
        }
      }
  }

  // ---- final streaming: X'' = X + delta12 -> global (single X write)
#pragma unroll
  for (int kt = 0; kt < 4; ++kt) {
    float4 a = *(const float4*)(XrowG + kt * 32 + g * 8);
    float4 b = *(const float4*)(XrowG + kt * 32 + g * 8 + 4);
    s16x8 d = *(const s16x8*)(VT + swz256(myrow, (kt * 32 + g * 8) * 2));
    *(float4*)(XrowG + kt * 32 + g * 8) = make_float4(
        a.x + bf2f((u16)d[0]), a.y + bf2f((u16)d[1]),
        a.z + bf2f((u16)d[2]), a.w + bf2f((u16)d[3]));
    *(float4*)(XrowG + kt * 32 + g * 8 + 4) = make_float4(
        b.x + bf2f((u16)d[4]), b.y + bf2f((u16)d[5]),
        b.z + bf2f((u16)d[6]), b.w + bf2f((u16)d[7]));
  }
}

// ---------------- readout ----------------
__global__ __launch_bounds__(256) void k_readout(
    const float* __restrict__ rex, const int* __restrict__ ori_idx,
    const int* __restrict__ reo_idx, const float* __restrict__ w_reg,
    const float* __restrict__ b_reg, float* __restrict__ out) {
  __shared__ float wl[3072];
  for (int i2 = threadIdx.x; i2 < 3072; i2 += 256) wl[i2] = w_reg[i2];
  __syncthreads();
  int b = blockIdx.x >> 7;
  int chunk = blockIdx.x & 127;
  int m = chunk * 64 + (threadIdx.x >> 2);
  int q = threadIdx.x & 3;
  int nOut = ori_idx[m];
  int j = reo_idx[m];
  int t = q >> 1;
  const float* src = rex + ((size_t)(b * 2 + t) * NODES + j) * D + (q & 1) * 64;
  float acc[12] = {0.f, 0.f, 0.f, 0.f, 0.f, 0.f, 0.f, 0.f, 0.f, 0.f, 0.f, 0.f};
#pragma unroll
  for (int k = 0; k < 64; k += 4) {
    float4 v = *(const float4*)(src + k);
#pragma unroll
    for (int o = 0; o < 12; ++o) {
      float4 wv = *(const float4*)(&wl[o * 256 + q * 64 + k]);
      acc[o] += v.x * wv.x + v.y * wv.y + v.z * wv.z + v.w * wv.w;
    }
  }
#pragma unroll
  for (int o = 0; o < 12; ++o) {
    acc[o] += __shfl_xor(acc[o], 1);
    acc[o] += __shfl_xor(acc[o], 2);
  }
  if (q == 0) {
#pragma unroll
    for (int o = 0; o < 12; ++o)
      out[((size_t)b * 12 + o) * NODES + nOut] = acc[o] + b_reg[o];
  }
}

// ---------------- host ----------------
extern "C" void kernel_launch(void* const* d_in, const int* in_sizes, int n_in,
                              void* d_out, int out_size, void* d_ws, size_t ws_size,
                              hipStream_t stream) {
  (void)in_sizes; (void)n_in; (void)out_size;
  const float* x = (const float*)d_in[0];
  const int* te = (const int*)d_in[1];
  const int* reo_all = (const int*)d_in[2];
  const int* ori_parts = (const int*)d_in[3];
  const int* reo_parts = (const int*)d_in[4];
  const float* w_st = (const float*)d_in[5];
  const float* b_st = (const float*)d_in[6];
  const float* node_emb = (const float*)d_in[7];
  const float* tod_emb = (const float*)d_in[8];
  const float* dow_emb = (const float*)d_in[9];
  const float* s_qkv_w = (const float*)d_in[10];
  const float* s_qkv_b = (const float*)d_in[11];
  const float* s_proj_w = (const float*)d_in[12];
  const float* s_proj_b = (const float*)d_in[13];
  const float* s_fc1_w = (const float*)d_in[14];
  const float* s_fc1_b = (const float*)d_in[15];
  const float* s_fc2_w = (const float*)d_in[16];
  const float* s_fc2_b = (const float*)d_in[17];
  const float* n_qkv_w = (const float*)d_in[18];
  const float* n_qkv_b = (const float*)d_in[19];
  const float* n_proj_w = (const float*)d_in[20];
  const float* n_proj_b = (const float*)d_in[21];
  const float* n_fc1_w = (const float*)d_in[22];
  const float* n_fc1_b = (const float*)d_in[23];
  const float* n_fc2_w = (const float*)d_in[24];
  const float* n_fc2_b = (const float*)d_in[25];
  const float* w_reg = (const float*)d_in[26];
  const float* b_reg = (const float*)d_in[27];
  (void)reo_all;

  const size_t REX_BYTES = (size_t)NB * TPN * NODES * D * 4;  // 134217728
  if (ws_size < REX_BYTES + 1179648) return;
  float* rex = (float*)d_ws;
  u16* wt = (u16*)((char*)d_ws + REX_BYTES);
  u16* s_qkv_t = wt + 0;
  u16* s_prj_t = wt + 147456;
  u16* s_fc1_t = wt + 196608;
  u16* s_fc2_t = wt + 245760;
  u16* n_qkv_t = wt + 294912;
  u16* n_prj_t = wt + 442368;
  u16* n_fc1_t = wt + 491520;
  u16* n_fc2_t = wt + 540672;

  k_prep<<<(3 * 128 * 384 + 255) / 256, 256, 0, stream>>>(s_qkv_w, s_qkv_t, 128, 384);
  k_prep<<<(3 * 128 * 128 + 255) / 256, 256, 0, stream>>>(s_proj_w, s_prj_t, 128, 128);
  k_prep<<<(3 * 128 * 128 + 255) / 256, 256, 0, stream>>>(s_fc1_w, s_fc1_t, 128, 128);
  k_prep<<<(3 * 128 * 128 + 255) / 256, 256, 0, stream>>>(s_fc2_w, s_fc2_t, 128, 128);
  k_prep<<<(3 * 128 * 384 + 255) / 256, 256, 0, stream>>>(n_qkv_w, n_qkv_t, 128, 384);
  k_prep<<<(3 * 128 * 128 + 255) / 256, 256, 0, stream>>>(n_proj_w, n_prj_t, 128, 128);
  k_prep<<<(3 * 128 * 128 + 255) / 256, 256, 0, stream>>>(n_fc1_w, n_fc1_t, 128, 128);
  k_prep<<<(3 * 128 * 128 + 255) / 256, 256, 0, stream>>>(n_fc2_w, n_fc2_t, 128, 128);

  k_embed<<<NB * TPN * (NODES / 16), 256, 0, stream>>>(
      x, te, reo_parts, w_st, b_st, node_emb, tod_emb, dow_emb, rex);

  for (int l = 0; l < 3; ++l) {
    k_fused<false><<<NB * TPN * (NODES / 256), 1024, 0, stream>>>(
        rex, s_qkv_t + (size_t)l * 49152, s_qkv_b + l * 384,
        s_prj_t + (size_t)l * 16384, s_proj_b + l * 128,
        s_fc1_t + (size_t)l * 16384, s_fc1_b + l * 128,
        s_fc2_t + (size_t)l * 16384, s_fc2_b + l * 128);
    k_fused<true><<<NB * TPN * NPS, 1024, 0, stream>>>(
        rex, n_qkv_t + (size_t)l * 49152, n_qkv_b + l * 384,
        n_prj_t + (size_t)l * 16384, n_proj_b + l * 128,
        n_fc1_t + (size_t)l * 16384, n_fc1_b + l * 128,
        n_fc2_t + (size_t)l * 16384, n_fc2_b + l * 128);
  }

  k_readout<<<NB * (NODES / 64), 256, 0, stream>>>(
      rex, ori_parts, reo_parts, w_reg, b_reg, (float*)d_out);
}